// Round 3
// baseline (766.796 us; speedup 1.0000x reference)
//
#include <hip/hip_runtime.h>

// GraphSAGE 2-layer encoder, MI355X (gfx950).  Round 3.
// - GEMM1 epilogue bounced through LDS -> 16-B coalesced bf16 stores
// - aggs: 16 B/lane, 2 rows/wave-load, 8 rows/iter, half-wave shfl combine
// - per-block int64 detection (no flag kernel), deg folded into k_misc

#define IN_DIM  1024
#define HID_DIM 256
#define OUT_N   512

typedef __attribute__((ext_vector_type(8))) short bf16x8;
typedef __attribute__((ext_vector_type(8))) unsigned short u16x8;
typedef __attribute__((ext_vector_type(4))) float f32x4;

static __device__ __forceinline__ unsigned short f2bf(float f) {
  unsigned int u = __float_as_uint(f);
  u += 0x7fffu + ((u >> 16) & 1u);
  return (unsigned short)(u >> 16);
}
static __device__ __forceinline__ float bf2f(unsigned short b) {
  return __uint_as_float(((unsigned int)b) << 16);
}

// int64 iff high dwords of first 4 entries are all zero (indices < 2^31).
// For int32 data these are 4 random node ids; P(all zero) ~ (2e-5)^4.
static __device__ __forceinline__ int detect64(const void* ei) {
  const unsigned int* p = (const unsigned int*)ei;
  return (p[1] | p[3] | p[5] | p[7]) == 0u;
}
static __device__ __forceinline__ int load_idx(const void* ei, long long pos, int is64) {
  if (is64) return (int)((const long long*)ei)[pos];
  return ((const int*)ei)[pos];
}

// ---------- fused: weight conversions + degree count ----------
// blocks [0,512): W1cat; [512,768): W2cat; [768,...): deg atomics
__global__ void k_misc(const void* __restrict__ ei, int nE,
                       const float* __restrict__ w1l, const float* __restrict__ w1r,
                       unsigned short* __restrict__ W1c,
                       const float* __restrict__ w2l, const float* __restrict__ w2r,
                       unsigned short* __restrict__ W2c, int* __restrict__ deg) {
  int b = blockIdx.x;
  if (b < 512) {                      // W1cat[n][k], n<256 -> w1_l else w1_r; K=1024
    int base = (b * 256 + threadIdx.x) * 4;
    int n = base / IN_DIM, k = base % IN_DIM;
    const float* s = (n < HID_DIM) ? &w1l[(size_t)n * IN_DIM + k]
                                   : &w1r[(size_t)(n - HID_DIM) * IN_DIM + k];
    float4 v = *(const float4*)s;
    ushort4 o = { f2bf(v.x), f2bf(v.y), f2bf(v.z), f2bf(v.w) };
    *(ushort4*)&W1c[base] = o;
  } else if (b < 768) {               // W2cat[n][k], k<256 -> w2_l else w2_r; K=512
    int base = ((b - 512) * 256 + threadIdx.x) * 4;
    int n = base >> 9, k = base & 511;
    const float* s = (k < HID_DIM) ? &w2l[(size_t)n * HID_DIM + k]
                                   : &w2r[(size_t)n * HID_DIM + (k - HID_DIM)];
    float4 v = *(const float4*)s;
    ushort4 o = { f2bf(v.x), f2bf(v.y), f2bf(v.z), f2bf(v.w) };
    *(ushort4*)&W2c[base] = o;
  } else {
    int e = (b - 768) * 256 + threadIdx.x;
    if (e >= nE) return;
    int is64 = detect64(ei);
    int d = load_idx(ei, (long long)nE + e, is64);
    atomicAdd(&deg[d], 1);
  }
}

__global__ void k_cvt_x(const float* __restrict__ x, unsigned short* __restrict__ xbf, int n4) {
  int i = blockIdx.x * 256 + threadIdx.x;
  if (i >= n4) return;
  float4 v = ((const float4*)x)[i];
  ushort4 o = { f2bf(v.x), f2bf(v.y), f2bf(v.z), f2bf(v.w) };
  ((ushort4*)xbf)[i] = o;
}

__global__ __launch_bounds__(1024) void k_scan(const int* __restrict__ deg,
                                               int* __restrict__ off, int n) {
  __shared__ int sums[1024];
  int t = threadIdx.x;
  int chunk = (n + 1023) >> 10;
  int base = t * chunk;
  int s = 0;
  for (int i = 0; i < chunk; ++i) { int idx = base + i; if (idx < n) s += deg[idx]; }
  sums[t] = s;
  __syncthreads();
  for (int d = 1; d < 1024; d <<= 1) {
    int v = 0;
    if (t >= d) v = sums[t - d];
    __syncthreads();
    sums[t] += v;
    __syncthreads();
  }
  int run = (t == 0) ? 0 : sums[t - 1];
  for (int i = 0; i < chunk; ++i) {
    int idx = base + i;
    if (idx < n) { off[idx] = run; run += deg[idx]; }
  }
  if (t == 1023) off[n] = run;
}

__global__ void k_fill(const void* __restrict__ ei, int nE,
                       const int* __restrict__ off, int* cursor, int* __restrict__ csr) {
  int e = blockIdx.x * 256 + threadIdx.x;
  if (e >= nE) return;
  int is64 = detect64(ei);
  int s = load_idx(ei, e, is64);
  int d = load_idx(ei, (long long)nE + e, is64);
  int p = atomicAdd(&cursor[d], 1);
  csr[off[d] + p] = s;
}

// ---------- GEMMs (m97-style: 128x128 tile, BK=32, 4 waves 2x2, 4x4 mfma) ----------
static __device__ __forceinline__ void load_lds16(const void* g, void* lds) {
  __builtin_amdgcn_global_load_lds(
      (const __attribute__((address_space(1))) unsigned int*)g,
      (__attribute__((address_space(3))) unsigned int*)lds, 16, 0, 0);
}

#define LSTRIDE 132   // fp32 epilogue row stride (16-B aligned, 2-way-free banks)

// GEMM1: A=[Mpad,1024] bf16, B=W1c[512,1024] bf16; out split Cl/Cr (+b1 on right)
__global__ __launch_bounds__(256) void k_gemm1(const unsigned short* __restrict__ A,
                                               const unsigned short* __restrict__ B,
                                               unsigned short* __restrict__ Cl,
                                               unsigned short* __restrict__ Cr,
                                               const float* __restrict__ b1) {
  __shared__ char SMEM[32 * LSTRIDE * 4];         // 16896 B >= 16384 staging
  unsigned short* As = (unsigned short*)SMEM;     // 8 KB
  unsigned short* Bs = As + 128 * 32;             // 8 KB
  const int tid = threadIdx.x;
  const int w = tid >> 6, l = tid & 63;
  const int wm = w >> 1, wn = w & 1;
  const int quad = l >> 4, lane16 = l & 15;
  const int m0 = blockIdx.y * 128;
  const int n0 = blockIdx.x * 128;

  f32x4 acc[4][4] = {};
  for (int k0 = 0; k0 < IN_DIM; k0 += 32) {
#pragma unroll
    for (int c = 0; c < 2; ++c) {
      const int flat = ((w * 2 + c) << 10);
      const int fb = flat + l * 16;
      const int row = fb >> 6;
      const int cb = fb & 63;
      load_lds16(A + (size_t)(m0 + row) * IN_DIM + (k0 + (cb >> 1)), (char*)As + flat);
      load_lds16(B + (size_t)(n0 + row) * IN_DIM + (k0 + (cb >> 1)), (char*)Bs + flat);
    }
    __syncthreads();
    bf16x8 af[4], bfr[4];
#pragma unroll
    for (int i = 0; i < 4; ++i)
      af[i] = *(const bf16x8*)&As[(wm * 64 + i * 16 + lane16) * 32 + quad * 8];
#pragma unroll
    for (int j = 0; j < 4; ++j)
      bfr[j] = *(const bf16x8*)&Bs[(wn * 64 + j * 16 + lane16) * 32 + quad * 8];
#pragma unroll
    for (int i = 0; i < 4; ++i)
#pragma unroll
      for (int j = 0; j < 4; ++j)
        acc[i][j] = __builtin_amdgcn_mfma_f32_16x16x32_bf16(af[i], bfr[j], acc[i][j], 0, 0, 0);
    __syncthreads();
  }

  // ---- epilogue: bounce 32x128 fp32 chunks through LDS, store 16-B coalesced ----
  const bool right = (n0 >= 256);
  unsigned short* Cb = right ? Cr : Cl;
  const int nc0 = n0 - (right ? 256 : 0);
  const int rrow = tid >> 3;                 // 0..31
  const int rcol = (tid & 7) * 16;           // 0..112
  float bias_r[16];
#pragma unroll
  for (int k = 0; k < 4; ++k) {
    if (right) *(float4*)&bias_r[k * 4] = *(const float4*)&b1[nc0 + rcol + k * 4];
    else { bias_r[k*4] = 0.f; bias_r[k*4+1] = 0.f; bias_r[k*4+2] = 0.f; bias_r[k*4+3] = 0.f; }
  }
  float* Ls = (float*)SMEM;
#pragma unroll
  for (int i = 0; i < 4; ++i) {
    __syncthreads();
    const int lr = wm * 16 + quad * 4;
#pragma unroll
    for (int j = 0; j < 4; ++j) {
      const int lc = wn * 64 + j * 16 + lane16;
#pragma unroll
      for (int r = 0; r < 4; ++r)
        Ls[(lr + r) * LSTRIDE + lc] = acc[i][j][r];
    }
    __syncthreads();
    float v[16];
#pragma unroll
    for (int k = 0; k < 4; ++k)
      *(float4*)&v[k * 4] = *(const float4*)&Ls[rrow * LSTRIDE + rcol + k * 4];
    u16x8 o0, o1;
#pragma unroll
    for (int k = 0; k < 8; ++k) {
      o0[k] = (short)f2bf(v[k] + bias_r[k]);
      o1[k] = (short)f2bf(v[k + 8] + bias_r[k + 8]);
    }
    const int grow = m0 + (rrow >> 4) * 64 + i * 16 + (rrow & 15);
    *(u16x8*)&Cb[(size_t)grow * HID_DIM + nc0 + rcol] = o0;
    *(u16x8*)&Cb[(size_t)grow * HID_DIM + nc0 + rcol + 8] = o1;
  }
}

// GEMM2: A k<256 from Am (mean2), k>=256 from Ah (h); B=W2c[512,512]; fp32 out + b2
__global__ __launch_bounds__(256) void k_gemm2(const unsigned short* __restrict__ Am,
                                               const unsigned short* __restrict__ Ah,
                                               const unsigned short* __restrict__ B,
                                               float* __restrict__ out,
                                               const float* __restrict__ b2, int Mstore) {
  __shared__ unsigned short As[128 * 32];
  __shared__ unsigned short Bs[128 * 32];
  const int tid = threadIdx.x;
  const int w = tid >> 6, l = tid & 63;
  const int wm = w >> 1, wn = w & 1;
  const int quad = l >> 4, lane16 = l & 15;
  const int m0 = blockIdx.y * 128;
  const int n0 = blockIdx.x * 128;

  f32x4 acc[4][4] = {};
  for (int k0 = 0; k0 < 2 * HID_DIM; k0 += 32) {
    const unsigned short* Abase = (k0 < HID_DIM) ? Am + k0 : Ah + (k0 - HID_DIM);
#pragma unroll
    for (int c = 0; c < 2; ++c) {
      const int flat = ((w * 2 + c) << 10);
      const int fb = flat + l * 16;
      const int row = fb >> 6;
      const int cb = fb & 63;
      load_lds16(Abase + (size_t)(m0 + row) * HID_DIM + (cb >> 1), (char*)As + flat);
      load_lds16(B + (size_t)(n0 + row) * (2 * HID_DIM) + (k0 + (cb >> 1)), (char*)Bs + flat);
    }
    __syncthreads();
    bf16x8 af[4], bfr[4];
#pragma unroll
    for (int i = 0; i < 4; ++i)
      af[i] = *(const bf16x8*)&As[(wm * 64 + i * 16 + lane16) * 32 + quad * 8];
#pragma unroll
    for (int j = 0; j < 4; ++j)
      bfr[j] = *(const bf16x8*)&Bs[(wn * 64 + j * 16 + lane16) * 32 + quad * 8];
#pragma unroll
    for (int i = 0; i < 4; ++i)
#pragma unroll
      for (int j = 0; j < 4; ++j)
        acc[i][j] = __builtin_amdgcn_mfma_f32_16x16x32_bf16(af[i], bfr[j], acc[i][j], 0, 0, 0);
    __syncthreads();
  }

#pragma unroll
  for (int i = 0; i < 4; ++i) {
    const int rbase = m0 + wm * 64 + i * 16 + quad * 4;
#pragma unroll
    for (int j = 0; j < 4; ++j) {
      const int col = n0 + wn * 64 + j * 16 + lane16;
      const float bv = b2[col];
#pragma unroll
      for (int r = 0; r < 4; ++r) {
        const int rowi = rbase + r;
        if (rowi < Mstore) out[(size_t)rowi * OUT_N + col] = acc[i][j][r] + bv;
      }
    }
  }
}

// ---------- aggregations: 1 wave/node, 16 B/lane, 2 rows per load, 8 rows/iter ----------
__global__ void k_agg1(const unsigned short* __restrict__ Cl,
                       const unsigned short* __restrict__ Cr,
                       const int* __restrict__ off, const int* __restrict__ csr,
                       unsigned short* __restrict__ h, int nNodes) {
  int node = blockIdx.x * 4 + (threadIdx.x >> 6);
  if (node >= nNodes) return;
  int l = threadIdx.x & 63;
  int half = l >> 5, lc = l & 31;
  int s = off[node], e = off[node + 1];
  float acc[8] = {};
  int i = s;
  for (; i + 8 <= e; i += 8) {
    int r0 = csr[i + half], r1 = csr[i + 2 + half], r2 = csr[i + 4 + half], r3 = csr[i + 6 + half];
    u16x8 v0 = *(const u16x8*)&Cl[(size_t)r0 * HID_DIM + lc * 8];
    u16x8 v1 = *(const u16x8*)&Cl[(size_t)r1 * HID_DIM + lc * 8];
    u16x8 v2 = *(const u16x8*)&Cl[(size_t)r2 * HID_DIM + lc * 8];
    u16x8 v3 = *(const u16x8*)&Cl[(size_t)r3 * HID_DIM + lc * 8];
#pragma unroll
    for (int k = 0; k < 8; ++k)
      acc[k] += (bf2f(v0[k]) + bf2f(v1[k])) + (bf2f(v2[k]) + bf2f(v3[k]));
  }
  for (; i + 2 <= e; i += 2) {
    int r0 = csr[i + half];
    u16x8 v0 = *(const u16x8*)&Cl[(size_t)r0 * HID_DIM + lc * 8];
#pragma unroll
    for (int k = 0; k < 8; ++k) acc[k] += bf2f(v0[k]);
  }
  if (i < e && half == 0) {
    int r0 = csr[i];
    u16x8 v0 = *(const u16x8*)&Cl[(size_t)r0 * HID_DIM + lc * 8];
#pragma unroll
    for (int k = 0; k < 8; ++k) acc[k] += bf2f(v0[k]);
  }
#pragma unroll
  for (int k = 0; k < 8; ++k) acc[k] += __shfl_xor(acc[k], 32);
  if (half == 0) {
    float inv = 1.0f / fmaxf((float)(e - s), 1.0f);
    u16x8 xr = *(const u16x8*)&Cr[(size_t)node * HID_DIM + lc * 8];   // includes b1
    u16x8 o;
#pragma unroll
    for (int k = 0; k < 8; ++k)
      o[k] = (short)f2bf(fmaxf(acc[k] * inv + bf2f(xr[k]), 0.0f));
    *(u16x8*)&h[(size_t)node * HID_DIM + lc * 8] = o;
  }
}

__global__ void k_agg2(const unsigned short* __restrict__ h,
                       const int* __restrict__ off, const int* __restrict__ csr,
                       unsigned short* __restrict__ mean2, int nNodes) {
  int node = blockIdx.x * 4 + (threadIdx.x >> 6);
  if (node >= nNodes) return;
  int l = threadIdx.x & 63;
  int half = l >> 5, lc = l & 31;
  int s = off[node], e = off[node + 1];
  float acc[8] = {};
  int i = s;
  for (; i + 8 <= e; i += 8) {
    int r0 = csr[i + half], r1 = csr[i + 2 + half], r2 = csr[i + 4 + half], r3 = csr[i + 6 + half];
    u16x8 v0 = *(const u16x8*)&h[(size_t)r0 * HID_DIM + lc * 8];
    u16x8 v1 = *(const u16x8*)&h[(size_t)r1 * HID_DIM + lc * 8];
    u16x8 v2 = *(const u16x8*)&h[(size_t)r2 * HID_DIM + lc * 8];
    u16x8 v3 = *(const u16x8*)&h[(size_t)r3 * HID_DIM + lc * 8];
#pragma unroll
    for (int k = 0; k < 8; ++k)
      acc[k] += (bf2f(v0[k]) + bf2f(v1[k])) + (bf2f(v2[k]) + bf2f(v3[k]));
  }
  for (; i + 2 <= e; i += 2) {
    int r0 = csr[i + half];
    u16x8 v0 = *(const u16x8*)&h[(size_t)r0 * HID_DIM + lc * 8];
#pragma unroll
    for (int k = 0; k < 8; ++k) acc[k] += bf2f(v0[k]);
  }
  if (i < e && half == 0) {
    int r0 = csr[i];
    u16x8 v0 = *(const u16x8*)&h[(size_t)r0 * HID_DIM + lc * 8];
#pragma unroll
    for (int k = 0; k < 8; ++k) acc[k] += bf2f(v0[k]);
  }
#pragma unroll
  for (int k = 0; k < 8; ++k) acc[k] += __shfl_xor(acc[k], 32);
  if (half == 0) {
    float inv = 1.0f / fmaxf((float)(e - s), 1.0f);
    u16x8 o;
#pragma unroll
    for (int k = 0; k < 8; ++k) o[k] = (short)f2bf(acc[k] * inv);
    *(u16x8*)&mean2[(size_t)node * HID_DIM + lc * 8] = o;
  }
}

extern "C" void kernel_launch(void* const* d_in, const int* in_sizes, int n_in,
                              void* d_out, int out_size, void* d_ws, size_t ws_size,
                              hipStream_t stream) {
  const float* x   = (const float*)d_in[0];
  const void*  ei  = d_in[1];
  const float* w1l = (const float*)d_in[2];
  const float* w1r = (const float*)d_in[3];
  const float* b1  = (const float*)d_in[4];
  const float* w2l = (const float*)d_in[5];
  const float* w2r = (const float*)d_in[6];
  const float* b2  = (const float*)d_in[7];
  float* out = (float*)d_out;

  const int nN   = in_sizes[0] / IN_DIM;         // 50000
  const int nE   = in_sizes[1] / 2;              // 800000
  const int Mpad = (nN + 127) & ~127;            // 50048

  char* ws = (char*)d_ws;
  size_t o = 0;
  auto alloc = [&](size_t bytes) {
    char* p = ws + o;
    o += (bytes + 255) & ~(size_t)255;
    return p;
  };
  unsigned short* xbf   = (unsigned short*)alloc((size_t)Mpad * IN_DIM * 2);
  unsigned short* W1c   = (unsigned short*)alloc((size_t)2 * HID_DIM * IN_DIM * 2);
  unsigned short* W2c   = (unsigned short*)alloc((size_t)OUT_N * 2 * HID_DIM * 2);
  unsigned short* Cl    = (unsigned short*)alloc((size_t)Mpad * HID_DIM * 2);
  unsigned short* Cr    = (unsigned short*)alloc((size_t)Mpad * HID_DIM * 2);
  unsigned short* hbuf  = (unsigned short*)alloc((size_t)Mpad * HID_DIM * 2);
  unsigned short* mean2 = (unsigned short*)alloc((size_t)Mpad * HID_DIM * 2);
  int* deg    = (int*)alloc((size_t)nN * 4);
  int* offs   = (int*)alloc((size_t)(nN + 1) * 4);
  int* cursor = (int*)alloc((size_t)nN * 4);
  int* csr    = (int*)alloc((size_t)nE * 4);

  hipMemsetAsync(deg, 0, (size_t)nN * 4, stream);
  hipMemsetAsync(cursor, 0, (size_t)nN * 4, stream);
  // pad rows of xbf / hbuf / mean2 stay 0xAA poison: decodes to ~1e-13 bf16,
  // flows only into pad rows / guarded stores -> never observed.

  const int degBlocks = (nE + 255) / 256;
  k_misc<<<768 + degBlocks, 256, 0, stream>>>(ei, nE, w1l, w1r, W1c, w2l, w2r, W2c, deg);
  k_cvt_x<<<(nN * IN_DIM / 4 + 255) / 256, 256, 0, stream>>>(x, xbf, nN * IN_DIM / 4);
  k_scan<<<1, 1024, 0, stream>>>(deg, offs, nN);
  k_fill<<<(nE + 255) / 256, 256, 0, stream>>>(ei, nE, offs, cursor, csr);

  dim3 g1(512 / 128, Mpad / 128);
  k_gemm1<<<g1, 256, 0, stream>>>(xbf, W1c, Cl, Cr, b1);
  k_agg1<<<(nN + 3) / 4, 256, 0, stream>>>(Cl, Cr, offs, csr, hbuf, nN);
  k_agg2<<<(nN + 3) / 4, 256, 0, stream>>>(hbuf, offs, csr, mean2, nN);
  k_gemm2<<<g1, 256, 0, stream>>>(mean2, hbuf, W2c, out, b2, nN);
}